// Round 2
// baseline (344.182 us; speedup 1.0000x reference)
//
#include <hip/hip_runtime.h>

// Problem constants (fixed by the reference)
#define Bn 8
#define Nn 50000
#define En 800000
#define Dd 64
#define CAP 64  // bucket capacity per node; P(in-degree >= 64) ~ 1e-18 (Binomial(800k,1/50k))

typedef __attribute__((ext_vector_type(8))) unsigned short ushort8;
typedef __attribute__((ext_vector_type(8))) __bf16 bf16x8;
typedef __attribute__((ext_vector_type(4))) float floatx4;

__device__ __forceinline__ unsigned short f2bf(float f) {
  unsigned int u = __builtin_bit_cast(unsigned int, f);
  u = (u + 0x7FFFu + ((u >> 16) & 1u)) >> 16;  // RNE
  return (unsigned short)u;
}

// XOR-swizzled byte offset into a [64][128]-ushort LDS tile (256B rows).
__device__ __forceinline__ int swz(int row, int byte_in_row) {
  return (row * 256 + byte_in_row) ^ ((row & 7) << 4);
}

// ---- 1. fused: x (f32) -> xb (bf16) + edge bucket build (spread across grid)
//      + W -> MFMA-fragment-layout bf16 (Wb) + bias sum (bb) ----
// Edge e handled by thread 8e: every wave carries 8 edges -> no straggler
// blocks (previously all 800k atomics+scatters sat in the first 3125 blocks).
__global__ __launch_bounds__(256) void k_fconv(const float* __restrict__ x,
                                               unsigned short* __restrict__ xb,
                                               const int* __restrict__ ei,
                                               int* __restrict__ deg,
                                               unsigned short* __restrict__ bucket,
                                               const float* __restrict__ Ws,
                                               const float* __restrict__ Wn,
                                               const float* __restrict__ bs,
                                               const float* __restrict__ bn,
                                               unsigned short* __restrict__ Wb,
                                               float* __restrict__ bb) {
  const size_t gid = (size_t)blockIdx.x * 256 + threadIdx.x;
  const size_t i = gid * 4;  // grid sized exactly: 6.4M threads
  const float4 v = *(const float4*)(x + i);
  ushort4 o;
  o.x = f2bf(v.x); o.y = f2bf(v.y); o.z = f2bf(v.z); o.w = f2bf(v.w);
  *(ushort4*)(xb + i) = o;
  if ((gid & 7) == 0) {  // gid>>3 covers exactly [0, En)
    const size_t e = gid >> 3;
    const int2 ep = *(const int2*)(ei + 2 * e);  // ep.x = src, ep.y = dst
    const int p = atomicAdd(&deg[ep.y], 1);
    if (p < CAP) bucket[((size_t)ep.y << 6) + p] = (unsigned short)ep.x;
  }
  if (gid < 1024) {
    // Wb fragment f = t*4+k, lane ln: 8 bf16 = W?[o=t*16+col][kd=k*32+quad*8 ..+8]
    const int f = (int)gid >> 6, ln = (int)gid & 63;
    const int t = f >> 2, k = f & 3;
    const int col = ln & 15, quad = ln >> 4;
    const int orow = t * 16 + col;
    const int kd = k * 32 + quad * 8;  // multiple of 8; never straddles 64
    const float* wsrc = (kd < 64) ? (Ws + orow * 64 + kd) : (Wn + orow * 64 + (kd - 64));
    ushort8 u;
    #pragma unroll
    for (int j = 0; j < 8; ++j) u[j] = f2bf(wsrc[j]);
    *(ushort8*)(Wb + gid * 8) = u;
  }
  if (gid < 64) bb[gid] = bs[gid] + bn[gid];
}

// ---- 2. fused: bucket-pull aggregate + MFMA + bias + relu ----
// batch = blockIdx.x & 7 pins each batch's 6.4MB xb slice to one XCD's L2.
// W is read straight from global (Wb, 16KB, L1-resident broadcast) -> LDS is
// A only (16KB). Each wave writes/reads ONLY its own 16 A-rows -> no barrier,
// waves fully decoupled. Target 8 blocks/CU.
__global__ __launch_bounds__(256, 8) void k_main(
    const unsigned short* __restrict__ xb, const unsigned short* __restrict__ bucket,
    const int* __restrict__ deg, const unsigned short* __restrict__ Wb,
    const float* __restrict__ bb, float* __restrict__ out) {
  __shared__ __align__(16) unsigned short A[64 * 128];  // [node][k]: k<64 self, k>=64 agg (swizzled), 16KB

  const int tid = threadIdx.x;
  const int b = blockIdx.x & 7;
  const int node0 = (blockIdx.x >> 3) * 64;
  const int wave = tid >> 6;
  const int lane = tid & 63;
  char* Ac = (char*)A;

  // ---- Phase A: 8 nodes per wave-pass, 8 lanes x 16B per row ----
  const int slot = lane >> 3;  // node within group
  const int li = lane & 7;     // dims li*8 .. li*8+7
  const size_t xb_base = (size_t)b * Nn * Dd + (size_t)(li * 8);

  for (int g = 0; g < 2; ++g) {
    const int nl = wave * 16 + g * 8 + slot;  // node_local; wave touches only its own 16 rows
    const int node = node0 + nl;
    float acc[8] = {0.f, 0.f, 0.f, 0.f, 0.f, 0.f, 0.f, 0.f};
    if (node < Nn) {
      // self row: independent, issue first so it rides under the gather chain
      const uint4 sv = *(const uint4*)(xb + xb_base + (size_t)node * Dd);
      const int cnt = min(deg[node], CAP);
      const unsigned short* bkt = bucket + (node << 6);
      const int nch = (cnt + 7) >> 3;  // always full chunks; pad = 0xFFFF sentinel
      for (int c = 0; c < nch; ++c) {
        // broadcast load: all 8 lanes of the slot read the same 16B of indices
        const uint4 e = *(const uint4*)(bkt + c * 8);
        const unsigned int ew[4] = {e.x, e.y, e.z, e.w};
        #pragma unroll
        for (int t = 0; t < 8; ++t) {
          unsigned int s = (ew[t >> 1] >> ((t & 1) * 16)) & 0xFFFFu;
          const float m = (s < (unsigned)Nn) ? 1.0f : 0.0f;  // sentinel mask
          s = min(s, (unsigned)(Nn - 1));                    // clamp to valid row
          const uint4 v = *(const uint4*)(xb + xb_base + (size_t)s * Dd);
          const unsigned int w[4] = {v.x, v.y, v.z, v.w};
          #pragma unroll
          for (int j = 0; j < 4; ++j) {  // 2 bf16 per u32; masked fma accumulate
            acc[2 * j]     = fmaf(m, __builtin_bit_cast(float, w[j] << 16), acc[2 * j]);
            acc[2 * j + 1] = fmaf(m, __builtin_bit_cast(float, w[j] & 0xFFFF0000u), acc[2 * j + 1]);
          }
        }
      }
      *(uint4*)(Ac + swz(nl, li * 16)) = sv;
    } else {
      *(uint4*)(Ac + swz(nl, li * 16)) = make_uint4(0, 0, 0, 0);
    }
    ushort8 av;
    #pragma unroll
    for (int j = 0; j < 8; ++j) av[j] = f2bf(acc[j]);
    *(ushort8*)(Ac + swz(nl, 128 + li * 16)) = av;
  }
  // no __syncthreads(): each wave consumes only the A-rows it wrote
  // (compiler orders ds_write -> ds_read via lgkmcnt within the wave)

  // ---- Phase B: 16x16x32 bf16 MFMA. Wave w: rows 16w..16w+15, all 64 outputs ----
  const int col = lane & 15;
  const int quad = lane >> 4;
  bf16x8 af[4];
  {
    const int row = wave * 16 + col;
    #pragma unroll
    for (int k = 0; k < 4; ++k)
      af[k] = __builtin_bit_cast(bf16x8, *(const ushort8*)(Ac + swz(row, quad * 16 + k * 64)));
  }
  #pragma unroll
  for (int t = 0; t < 4; ++t) {
    floatx4 acc = {0.f, 0.f, 0.f, 0.f};
    #pragma unroll
    for (int k = 0; k < 4; ++k) {
      // fragment-layout W: fully coalesced 16B/lane, L1-resident (16KB total)
      bf16x8 bf = __builtin_bit_cast(bf16x8, *(const ushort8*)(Wb + ((t * 4 + k) * 64 + lane) * 8));
      acc = __builtin_amdgcn_mfma_f32_16x16x32_bf16(af[k], bf, acc, 0, 0, 0);
    }
    const float bv = bb[t * 16 + col];  // precomputed bs+bn, L2-hot
    #pragma unroll
    for (int r = 0; r < 4; ++r) {
      const int node = node0 + wave * 16 + quad * 4 + r;
      if (node < Nn) {
        float v = acc[r] + bv;
        out[((size_t)b * Nn + node) * Dd + t * 16 + col] = v > 0.f ? v : 0.f;
      }
    }
  }
}

// ---- workspace layout ----
#define OFF_XB 0ull          // 51,200,000 B (bf16 x)
#define OFF_DEG 51200000ull  //    200,000 B (int per node)
#define OFF_BKT 51400000ull  //  6,400,000 B (ushort src, CAP=64 per node)
#define OFF_WB 57800000ull   //     16,384 B (bf16 W in MFMA fragment layout)
#define OFF_BB 57816384ull   //        256 B (f32 bias sum)
#define WS_NEED 57816640ull

extern "C" void kernel_launch(void* const* d_in, const int* in_sizes, int n_in,
                              void* d_out, int out_size, void* d_ws,
                              size_t ws_size, hipStream_t stream) {
  const float* x = (const float*)d_in[0];
  const int* ei = (const int*)d_in[1];  // (E,2) int32: [src,dst]
  const float* Ws = (const float*)d_in[2];
  const float* bs = (const float*)d_in[3];
  const float* Wn = (const float*)d_in[4];
  const float* bn = (const float*)d_in[5];
  float* out = (float*)d_out;

  if (ws_size < WS_NEED) return;

  char* ws = (char*)d_ws;
  unsigned short* xb = (unsigned short*)(ws + OFF_XB);
  int* deg = (int*)(ws + OFF_DEG);
  unsigned short* bucket = (unsigned short*)(ws + OFF_BKT);
  unsigned short* Wb = (unsigned short*)(ws + OFF_WB);
  float* bb = (float*)(ws + OFF_BB);

  hipMemsetAsync(deg, 0, Nn * sizeof(int), stream);
  hipMemsetAsync(bucket, 0xFF, (size_t)Nn * CAP * sizeof(unsigned short), stream);  // sentinel fill
  k_fconv<<<(Bn * Nn * Dd / 4) / 256, 256, 0, stream>>>(x, xb, ei, deg, bucket, Ws, Wn, bs, bn, Wb, bb);
  const int ntiles = (Nn + 63) / 64;  // 782
  k_main<<<ntiles * Bn, 256, 0, stream>>>(xb, bucket, deg, Wb, bb, out);
}

// Round 3
// 319.075 us; speedup vs baseline: 1.0787x; 1.0787x over previous
//
#include <hip/hip_runtime.h>

// Problem constants (fixed by the reference)
#define Bn 8
#define Nn 50000
#define En 800000
#define Dd 64
#define CAP 64  // bucket capacity per node; P(in-degree >= 64) ~ 1e-18 (Binomial(800k,1/50k))

typedef __attribute__((ext_vector_type(8))) unsigned short ushort8;
typedef __attribute__((ext_vector_type(8))) __bf16 bf16x8;
typedef __attribute__((ext_vector_type(4))) float floatx4;

__device__ __forceinline__ unsigned short f2bf(float f) {
  unsigned int u = __builtin_bit_cast(unsigned int, f);
  u = (u + 0x7FFFu + ((u >> 16) & 1u)) >> 16;  // RNE
  return (unsigned short)u;
}

// XOR-swizzled byte offset into a [64][128]-ushort LDS tile (256B rows).
__device__ __forceinline__ int swz(int row, int byte_in_row) {
  return (row * 256 + byte_in_row) ^ ((row & 7) << 4);
}

// ---- 1. fused: x (f32) -> xb (bf16) + edge bucket build (spread across grid)
//      + W -> MFMA-fragment-layout bf16 (Wb) + bias sum (bb) ----
// No bucket memset needed: k_main masks by slot<cnt, so garbage is never read.
__global__ __launch_bounds__(256) void k_fconv(const float* __restrict__ x,
                                               unsigned short* __restrict__ xb,
                                               const int* __restrict__ ei,
                                               int* __restrict__ deg,
                                               unsigned short* __restrict__ bucket,
                                               const float* __restrict__ Ws,
                                               const float* __restrict__ Wn,
                                               const float* __restrict__ bs,
                                               const float* __restrict__ bn,
                                               unsigned short* __restrict__ Wb,
                                               float* __restrict__ bb) {
  const size_t gid = (size_t)blockIdx.x * 256 + threadIdx.x;
  const size_t i = gid * 4;  // grid sized exactly: 6.4M threads
  const float4 v = *(const float4*)(x + i);
  ushort4 o;
  o.x = f2bf(v.x); o.y = f2bf(v.y); o.z = f2bf(v.z); o.w = f2bf(v.w);
  *(ushort4*)(xb + i) = o;
  if ((gid & 7) == 0) {  // gid>>3 covers exactly [0, En): 8 edges per wave
    const size_t e = gid >> 3;
    const int2 ep = *(const int2*)(ei + 2 * e);  // ep.x = src, ep.y = dst
    const int p = atomicAdd(&deg[ep.y], 1);
    if (p < CAP) bucket[((size_t)ep.y << 6) + p] = (unsigned short)ep.x;
  }
  if (gid < 1024) {
    // Wb fragment f = t*4+k, lane ln: 8 bf16 = W?[o=t*16+col][kd=k*32+quad*8 ..+8]
    const int f = (int)gid >> 6, ln = (int)gid & 63;
    const int t = f >> 2, k = f & 3;
    const int col = ln & 15, quad = ln >> 4;
    const int orow = t * 16 + col;
    const int kd = k * 32 + quad * 8;  // multiple of 8; never straddles 64
    const float* wsrc = (kd < 64) ? (Ws + orow * 64 + kd) : (Wn + orow * 64 + (kd - 64));
    ushort8 u;
    #pragma unroll
    for (int j = 0; j < 8; ++j) u[j] = f2bf(wsrc[j]);
    *(ushort8*)(Wb + gid * 8) = u;
  }
  if (gid < 64) bb[gid] = bs[gid] + bn[gid];
}

// ---- 2. fused: bucket-pull aggregate + MFMA + bias + relu ----
// batch = blockIdx.x & 7 pins each batch's 6.4MB xb slice to one XCD's L2.
// (256,3): ~3 blocks/CU — R2 proved higher concurrency thrashes L2 (traffic
// +70%); instead spend registers on ILP: 16 gathers in flight per wave
// (both 8-node groups interleaved) + next-chunk index prefetch.
__global__ __launch_bounds__(256, 3) void k_main(
    const unsigned short* __restrict__ xb, const unsigned short* __restrict__ bucket,
    const int* __restrict__ deg, const unsigned short* __restrict__ Wb,
    const float* __restrict__ bb, float* __restrict__ out) {
  __shared__ __align__(16) unsigned short A[64 * 128];  // [node][k]: k<64 self, k>=64 agg (swizzled), 16KB

  const int tid = threadIdx.x;
  const int b = blockIdx.x & 7;
  const int node0 = (blockIdx.x >> 3) * 64;
  const int wave = tid >> 6;
  const int lane = tid & 63;
  char* Ac = (char*)A;

  // ---- Phase A: 16 nodes per wave in ONE pass; 8 lanes x 16B per row ----
  const int slot = lane >> 3;  // node within group (0..7)
  const int li = lane & 7;     // dims li*8 .. li*8+7
  const size_t xb_base = (size_t)b * Nn * Dd + (size_t)(li * 8);

  const int nl0 = wave * 16 + slot;  // group-0 node_local
  const int nl1 = nl0 + 8;           // group-1 node_local
  const int n0 = node0 + nl0;
  const int n1 = node0 + nl1;
  const bool v0 = n0 < Nn, v1 = n1 < Nn;
  const int n0c = v0 ? n0 : 0, n1c = v1 ? n1 : 0;

  const int cnt0 = v0 ? min(deg[n0c], CAP) : 0;
  const int cnt1 = v1 ? min(deg[n1c], CAP) : 0;
  const unsigned short* bkt0 = bucket + ((size_t)n0c << 6);
  const unsigned short* bkt1 = bucket + ((size_t)n1c << 6);

  // self rows: independent loads, issue at the head of the chain
  uint4 sv0 = *(const uint4*)(xb + xb_base + (size_t)n0c * Dd);
  uint4 sv1 = *(const uint4*)(xb + xb_base + (size_t)n1c * Dd);

  const int nch0 = (cnt0 + 7) >> 3;
  const int nch1 = (cnt1 + 7) >> 3;
  const int nch = max(nch0, nch1);

  float a0[8] = {0.f, 0.f, 0.f, 0.f, 0.f, 0.f, 0.f, 0.f};
  float a1[8] = {0.f, 0.f, 0.f, 0.f, 0.f, 0.f, 0.f, 0.f};

  uint4 e0 = make_uint4(0, 0, 0, 0), e1 = e0;
  if (nch > 0) {  // first index chunks (16B broadcast per 8-lane slot group)
    e0 = *(const uint4*)(bkt0);
    e1 = *(const uint4*)(bkt1);
  }
  for (int c = 0; c < nch; ++c) {
    uint4 ne0 = e0, ne1 = e1;
    if (c + 1 < nch) {  // prefetch next chunk's indices under this chunk's work
      ne0 = *(const uint4*)(bkt0 + (c + 1) * 8);
      ne1 = *(const uint4*)(bkt1 + (c + 1) * 8);
    }
    const unsigned int ew0[4] = {e0.x, e0.y, e0.z, e0.w};
    const unsigned int ew1[4] = {e1.x, e1.y, e1.z, e1.w};
    uint4 g0[8], g1[8];
    float m0[8], m1[8];
    // issue all 16 gathers before any unpack: 16 loads in flight
    #pragma unroll
    for (int t = 0; t < 8; ++t) {
      unsigned int s = (ew0[t >> 1] >> ((t & 1) * 16)) & 0xFFFFu;
      const bool live = (c * 8 + t) < cnt0;
      m0[t] = live ? 1.0f : 0.0f;
      s = live ? min(s, (unsigned)(Nn - 1)) : (unsigned)(Nn - 1);  // junk -> L1-hot row
      g0[t] = *(const uint4*)(xb + xb_base + (size_t)s * Dd);
    }
    #pragma unroll
    for (int t = 0; t < 8; ++t) {
      unsigned int s = (ew1[t >> 1] >> ((t & 1) * 16)) & 0xFFFFu;
      const bool live = (c * 8 + t) < cnt1;
      m1[t] = live ? 1.0f : 0.0f;
      s = live ? min(s, (unsigned)(Nn - 1)) : (unsigned)(Nn - 1);
      g1[t] = *(const uint4*)(xb + xb_base + (size_t)s * Dd);
    }
    #pragma unroll
    for (int t = 0; t < 8; ++t) {
      const unsigned int* w = (const unsigned int*)&g0[t];
      #pragma unroll
      for (int j = 0; j < 4; ++j) {  // 2 bf16 per u32; masked fma accumulate
        a0[2 * j]     = fmaf(m0[t], __builtin_bit_cast(float, w[j] << 16), a0[2 * j]);
        a0[2 * j + 1] = fmaf(m0[t], __builtin_bit_cast(float, w[j] & 0xFFFF0000u), a0[2 * j + 1]);
      }
    }
    #pragma unroll
    for (int t = 0; t < 8; ++t) {
      const unsigned int* w = (const unsigned int*)&g1[t];
      #pragma unroll
      for (int j = 0; j < 4; ++j) {
        a1[2 * j]     = fmaf(m1[t], __builtin_bit_cast(float, w[j] << 16), a1[2 * j]);
        a1[2 * j + 1] = fmaf(m1[t], __builtin_bit_cast(float, w[j] & 0xFFFF0000u), a1[2 * j + 1]);
      }
    }
    e0 = ne0; e1 = ne1;
  }

  // A-tile stores (wave-private rows: no barrier needed anywhere)
  if (!v0) sv0 = make_uint4(0, 0, 0, 0);
  if (!v1) sv1 = make_uint4(0, 0, 0, 0);
  *(uint4*)(Ac + swz(nl0, li * 16)) = sv0;
  *(uint4*)(Ac + swz(nl1, li * 16)) = sv1;
  ushort8 av0, av1;
  #pragma unroll
  for (int j = 0; j < 8; ++j) { av0[j] = f2bf(a0[j]); av1[j] = f2bf(a1[j]); }
  *(ushort8*)(Ac + swz(nl0, 128 + li * 16)) = av0;
  *(ushort8*)(Ac + swz(nl1, 128 + li * 16)) = av1;

  // ---- Phase B: 16x16x32 bf16 MFMA. Wave w: rows 16w..16w+15, all 64 outputs ----
  const int col = lane & 15;
  const int quad = lane >> 4;
  bf16x8 af[4];
  {
    const int row = wave * 16 + col;
    #pragma unroll
    for (int k = 0; k < 4; ++k)
      af[k] = __builtin_bit_cast(bf16x8, *(const ushort8*)(Ac + swz(row, quad * 16 + k * 64)));
  }
  #pragma unroll
  for (int t = 0; t < 4; ++t) {
    floatx4 acc = {0.f, 0.f, 0.f, 0.f};
    #pragma unroll
    for (int k = 0; k < 4; ++k) {
      // fragment-layout W: fully coalesced 16B/lane, L1-resident (16KB total)
      bf16x8 bf = __builtin_bit_cast(bf16x8, *(const ushort8*)(Wb + ((t * 4 + k) * 64 + lane) * 8));
      acc = __builtin_amdgcn_mfma_f32_16x16x32_bf16(af[k], bf, acc, 0, 0, 0);
    }
    const float bv = bb[t * 16 + col];  // precomputed bs+bn, L2-hot
    #pragma unroll
    for (int r = 0; r < 4; ++r) {
      const int node = node0 + wave * 16 + quad * 4 + r;
      if (node < Nn) {
        float v = acc[r] + bv;
        out[((size_t)b * Nn + node) * Dd + t * 16 + col] = v > 0.f ? v : 0.f;
      }
    }
  }
}

// ---- workspace layout ----
#define OFF_XB 0ull          // 51,200,000 B (bf16 x)
#define OFF_DEG 51200000ull  //    200,000 B (int per node)
#define OFF_BKT 51400000ull  //  6,400,000 B (ushort src, CAP=64 per node)
#define OFF_WB 57800000ull   //     16,384 B (bf16 W in MFMA fragment layout)
#define OFF_BB 57816384ull   //        256 B (f32 bias sum)
#define WS_NEED 57816640ull

extern "C" void kernel_launch(void* const* d_in, const int* in_sizes, int n_in,
                              void* d_out, int out_size, void* d_ws,
                              size_t ws_size, hipStream_t stream) {
  const float* x = (const float*)d_in[0];
  const int* ei = (const int*)d_in[1];  // (E,2) int32: [src,dst]
  const float* Ws = (const float*)d_in[2];
  const float* bs = (const float*)d_in[3];
  const float* Wn = (const float*)d_in[4];
  const float* bn = (const float*)d_in[5];
  float* out = (float*)d_out;

  if (ws_size < WS_NEED) return;

  char* ws = (char*)d_ws;
  unsigned short* xb = (unsigned short*)(ws + OFF_XB);
  int* deg = (int*)(ws + OFF_DEG);
  unsigned short* bucket = (unsigned short*)(ws + OFF_BKT);
  unsigned short* Wb = (unsigned short*)(ws + OFF_WB);
  float* bb = (float*)(ws + OFF_BB);

  hipMemsetAsync(deg, 0, Nn * sizeof(int), stream);
  // no bucket memset: k_main masks by (slot < cnt), junk slots never used
  k_fconv<<<(Bn * Nn * Dd / 4) / 256, 256, 0, stream>>>(x, xb, ei, deg, bucket, Ws, Wn, bs, bn, Wb, bb);
  const int ntiles = (Nn + 63) / 64;  // 782
  k_main<<<ntiles * Bn, 256, 0, stream>>>(xb, bucket, deg, Wb, bb, out);
}

// Round 4
// 305.338 us; speedup vs baseline: 1.1272x; 1.0450x over previous
//
#include <hip/hip_runtime.h>

// Problem constants (fixed by the reference)
#define Bn 8
#define Nn 50000
#define En 800000
#define Dd 64
#define CAP 64  // bucket capacity per node; P(in-degree >= 64) ~ 1e-18 (Binomial(800k,1/50k))

typedef __attribute__((ext_vector_type(8))) unsigned short ushort8;
typedef __attribute__((ext_vector_type(8))) __bf16 bf16x8;
typedef __attribute__((ext_vector_type(4))) float floatx4;
typedef __attribute__((ext_vector_type(2))) int intx2;

__device__ __forceinline__ unsigned short f2bf(float f) {
  unsigned int u = __builtin_bit_cast(unsigned int, f);
  u = (u + 0x7FFFu + ((u >> 16) & 1u)) >> 16;  // RNE
  return (unsigned short)u;
}

// XOR-swizzled byte offset into a [64][128]-ushort LDS tile (256B rows).
__device__ __forceinline__ int swz(int row, int byte_in_row) {
  return (row * 256 + byte_in_row) ^ ((row & 7) << 4);
}

// ---- 1. fused: x (f32) -> xb (bf16) + edge bucket build + W/bias prep ----
// x and ei are dead after this kernel -> NON-TEMPORAL loads so they don't
// evict xb/bucket from L3 (k_main's gathers need xb L3-resident).
// 8 f32/thread: half the waves of R3 for the same stream.
__global__ __launch_bounds__(256) void k_fconv(const float* __restrict__ x,
                                               unsigned short* __restrict__ xb,
                                               const int* __restrict__ ei,
                                               int* __restrict__ deg,
                                               unsigned short* __restrict__ bucket,
                                               const float* __restrict__ Ws,
                                               const float* __restrict__ Wn,
                                               const float* __restrict__ bs,
                                               const float* __restrict__ bn,
                                               unsigned short* __restrict__ Wb,
                                               float* __restrict__ bb) {
  const size_t gid = (size_t)blockIdx.x * 256 + threadIdx.x;
  const size_t i = gid * 8;  // grid sized exactly: 3.2M threads x 8 f32
  const floatx4 v0 = __builtin_nontemporal_load((const floatx4*)(x + i));
  const floatx4 v1 = __builtin_nontemporal_load((const floatx4*)(x + i + 4));
  ushort8 o;
  o[0] = f2bf(v0.x); o[1] = f2bf(v0.y); o[2] = f2bf(v0.z); o[3] = f2bf(v0.w);
  o[4] = f2bf(v1.x); o[5] = f2bf(v1.y); o[6] = f2bf(v1.z); o[7] = f2bf(v1.w);
  *(ushort8*)(xb + i) = o;  // temporal: xb must stay L3-resident for k_main
  if ((gid & 3) == 0) {  // gid>>2 covers exactly [0, En): 16 edges per wave
    const size_t e = gid >> 2;
    const intx2 ep = __builtin_nontemporal_load((const intx2*)(ei + 2 * e));  // [src,dst]
    const int p = atomicAdd(&deg[ep.y], 1);
    if (p < CAP) bucket[((size_t)ep.y << 6) + p] = (unsigned short)ep.x;
  }
  if (gid < 1024) {
    // Wb fragment f = t*4+k, lane ln: 8 bf16 = W?[o=t*16+col][kd=k*32+quad*8 ..+8]
    const int f = (int)gid >> 6, ln = (int)gid & 63;
    const int t = f >> 2, k = f & 3;
    const int col = ln & 15, quad = ln >> 4;
    const int orow = t * 16 + col;
    const int kd = k * 32 + quad * 8;  // multiple of 8; never straddles 64
    const float* wsrc = (kd < 64) ? (Ws + orow * 64 + kd) : (Wn + orow * 64 + (kd - 64));
    ushort8 u;
    #pragma unroll
    for (int j = 0; j < 8; ++j) u[j] = f2bf(wsrc[j]);
    *(ushort8*)(Wb + gid * 8) = u;
  }
  if (gid < 64) bb[gid] = bs[gid] + bn[gid];
}

// ---- 2. fused: bucket-pull aggregate + MFMA + bias + relu ----
// batch = blockIdx.x & 7 pins each batch's 6.4MB xb slice to one XCD's L2.
// (256,4): 16-wave TLP (R1's ~13-wave regime won over R3's 12-cap and R2's
// 24-wave L2-thrash). ILP kept: 16 gathers in flight + index prefetch.
// out stores NON-TEMPORAL: 102MB pure stream, never re-read -> don't let it
// evict xb from L2/L3.
__global__ __launch_bounds__(256, 4) void k_main(
    const unsigned short* __restrict__ xb, const unsigned short* __restrict__ bucket,
    const int* __restrict__ deg, const unsigned short* __restrict__ Wb,
    const float* __restrict__ bb, float* __restrict__ out) {
  __shared__ __align__(16) unsigned short A[64 * 128];  // [node][k]: k<64 self, k>=64 agg (swizzled), 16KB

  const int tid = threadIdx.x;
  const int b = blockIdx.x & 7;
  const int node0 = (blockIdx.x >> 3) * 64;
  const int wave = tid >> 6;
  const int lane = tid & 63;
  char* Ac = (char*)A;

  // ---- Phase A: 16 nodes per wave in ONE pass; 8 lanes x 16B per row ----
  const int slot = lane >> 3;  // node within group (0..7)
  const int li = lane & 7;     // dims li*8 .. li*8+7
  const size_t xb_base = (size_t)b * Nn * Dd + (size_t)(li * 8);

  const int nl0 = wave * 16 + slot;  // group-0 node_local
  const int nl1 = nl0 + 8;           // group-1 node_local
  const int n0 = node0 + nl0;
  const int n1 = node0 + nl1;
  const bool v0 = n0 < Nn, v1 = n1 < Nn;
  const int n0c = v0 ? n0 : 0, n1c = v1 ? n1 : 0;

  const int cnt0 = v0 ? min(deg[n0c], CAP) : 0;
  const int cnt1 = v1 ? min(deg[n1c], CAP) : 0;
  const unsigned short* bkt0 = bucket + ((size_t)n0c << 6);
  const unsigned short* bkt1 = bucket + ((size_t)n1c << 6);

  // self rows: independent loads, issue at the head of the chain
  uint4 sv0 = *(const uint4*)(xb + xb_base + (size_t)n0c * Dd);
  uint4 sv1 = *(const uint4*)(xb + xb_base + (size_t)n1c * Dd);

  const int nch0 = (cnt0 + 7) >> 3;
  const int nch1 = (cnt1 + 7) >> 3;
  const int nch = max(nch0, nch1);

  float a0[8] = {0.f, 0.f, 0.f, 0.f, 0.f, 0.f, 0.f, 0.f};
  float a1[8] = {0.f, 0.f, 0.f, 0.f, 0.f, 0.f, 0.f, 0.f};

  uint4 e0 = make_uint4(0, 0, 0, 0), e1 = e0;
  if (nch > 0) {  // first index chunks (16B broadcast per 8-lane slot group)
    e0 = *(const uint4*)(bkt0);
    e1 = *(const uint4*)(bkt1);
  }
  for (int c = 0; c < nch; ++c) {
    uint4 ne0 = e0, ne1 = e1;
    if (c + 1 < nch) {  // prefetch next chunk's indices under this chunk's work
      ne0 = *(const uint4*)(bkt0 + (c + 1) * 8);
      ne1 = *(const uint4*)(bkt1 + (c + 1) * 8);
    }
    const unsigned int ew0[4] = {e0.x, e0.y, e0.z, e0.w};
    const unsigned int ew1[4] = {e1.x, e1.y, e1.z, e1.w};
    uint4 g0[8], g1[8];
    float m0[8], m1[8];
    // issue all 16 gathers before any unpack: 16 loads in flight
    #pragma unroll
    for (int t = 0; t < 8; ++t) {
      unsigned int s = (ew0[t >> 1] >> ((t & 1) * 16)) & 0xFFFFu;
      const bool live = (c * 8 + t) < cnt0;
      m0[t] = live ? 1.0f : 0.0f;
      s = live ? min(s, (unsigned)(Nn - 1)) : (unsigned)(Nn - 1);  // junk -> hot row
      g0[t] = *(const uint4*)(xb + xb_base + (size_t)s * Dd);
    }
    #pragma unroll
    for (int t = 0; t < 8; ++t) {
      unsigned int s = (ew1[t >> 1] >> ((t & 1) * 16)) & 0xFFFFu;
      const bool live = (c * 8 + t) < cnt1;
      m1[t] = live ? 1.0f : 0.0f;
      s = live ? min(s, (unsigned)(Nn - 1)) : (unsigned)(Nn - 1);
      g1[t] = *(const uint4*)(xb + xb_base + (size_t)s * Dd);
    }
    #pragma unroll
    for (int t = 0; t < 8; ++t) {
      const unsigned int* w = (const unsigned int*)&g0[t];
      #pragma unroll
      for (int j = 0; j < 4; ++j) {  // 2 bf16 per u32; masked fma accumulate
        a0[2 * j]     = fmaf(m0[t], __builtin_bit_cast(float, w[j] << 16), a0[2 * j]);
        a0[2 * j + 1] = fmaf(m0[t], __builtin_bit_cast(float, w[j] & 0xFFFF0000u), a0[2 * j + 1]);
      }
    }
    #pragma unroll
    for (int t = 0; t < 8; ++t) {
      const unsigned int* w = (const unsigned int*)&g1[t];
      #pragma unroll
      for (int j = 0; j < 4; ++j) {
        a1[2 * j]     = fmaf(m1[t], __builtin_bit_cast(float, w[j] << 16), a1[2 * j]);
        a1[2 * j + 1] = fmaf(m1[t], __builtin_bit_cast(float, w[j] & 0xFFFF0000u), a1[2 * j + 1]);
      }
    }
    e0 = ne0; e1 = ne1;
  }

  // A-tile stores (wave-private rows: no barrier needed anywhere)
  if (!v0) sv0 = make_uint4(0, 0, 0, 0);
  if (!v1) sv1 = make_uint4(0, 0, 0, 0);
  *(uint4*)(Ac + swz(nl0, li * 16)) = sv0;
  *(uint4*)(Ac + swz(nl1, li * 16)) = sv1;
  ushort8 av0, av1;
  #pragma unroll
  for (int j = 0; j < 8; ++j) { av0[j] = f2bf(a0[j]); av1[j] = f2bf(a1[j]); }
  *(ushort8*)(Ac + swz(nl0, 128 + li * 16)) = av0;
  *(ushort8*)(Ac + swz(nl1, 128 + li * 16)) = av1;

  // ---- Phase B: 16x16x32 bf16 MFMA. Wave w: rows 16w..16w+15, all 64 outputs ----
  const int col = lane & 15;
  const int quad = lane >> 4;
  bf16x8 af[4];
  {
    const int row = wave * 16 + col;
    #pragma unroll
    for (int k = 0; k < 4; ++k)
      af[k] = __builtin_bit_cast(bf16x8, *(const ushort8*)(Ac + swz(row, quad * 16 + k * 64)));
  }
  #pragma unroll
  for (int t = 0; t < 4; ++t) {
    floatx4 acc = {0.f, 0.f, 0.f, 0.f};
    #pragma unroll
    for (int k = 0; k < 4; ++k) {
      // fragment-layout W: fully coalesced 16B/lane, L1-resident (16KB total)
      bf16x8 bf = __builtin_bit_cast(bf16x8, *(const ushort8*)(Wb + ((t * 4 + k) * 64 + lane) * 8));
      acc = __builtin_amdgcn_mfma_f32_16x16x32_bf16(af[k], bf, acc, 0, 0, 0);
    }
    const float bv = bb[t * 16 + col];  // precomputed bs+bn, L2-hot
    #pragma unroll
    for (int r = 0; r < 4; ++r) {
      const int node = node0 + wave * 16 + quad * 4 + r;
      if (node < Nn) {
        float v = acc[r] + bv;
        __builtin_nontemporal_store(v > 0.f ? v : 0.f,
                                    &out[((size_t)b * Nn + node) * Dd + t * 16 + col]);
      }
    }
  }
}

// ---- workspace layout ----
#define OFF_XB 0ull          // 51,200,000 B (bf16 x)
#define OFF_DEG 51200000ull  //    200,000 B (int per node)
#define OFF_BKT 51400000ull  //  6,400,000 B (ushort src, CAP=64 per node)
#define OFF_WB 57800000ull   //     16,384 B (bf16 W in MFMA fragment layout)
#define OFF_BB 57816384ull   //        256 B (f32 bias sum)
#define WS_NEED 57816640ull

extern "C" void kernel_launch(void* const* d_in, const int* in_sizes, int n_in,
                              void* d_out, int out_size, void* d_ws,
                              size_t ws_size, hipStream_t stream) {
  const float* x = (const float*)d_in[0];
  const int* ei = (const int*)d_in[1];  // (E,2) int32: [src,dst]
  const float* Ws = (const float*)d_in[2];
  const float* bs = (const float*)d_in[3];
  const float* Wn = (const float*)d_in[4];
  const float* bn = (const float*)d_in[5];
  float* out = (float*)d_out;

  if (ws_size < WS_NEED) return;

  char* ws = (char*)d_ws;
  unsigned short* xb = (unsigned short*)(ws + OFF_XB);
  int* deg = (int*)(ws + OFF_DEG);
  unsigned short* bucket = (unsigned short*)(ws + OFF_BKT);
  unsigned short* Wb = (unsigned short*)(ws + OFF_WB);
  float* bb = (float*)(ws + OFF_BB);

  hipMemsetAsync(deg, 0, Nn * sizeof(int), stream);
  // no bucket memset: k_main masks by (slot < cnt), junk slots never used
  k_fconv<<<(Bn * Nn * Dd / 8) / 256, 256, 0, stream>>>(x, xb, ei, deg, bucket, Ws, Wn, bs, bn, Wb, bb);
  const int ntiles = (Nn + 63) / 64;  // 782
  k_main<<<ntiles * Bn, 256, 0, stream>>>(xb, bucket, deg, Wb, bb, out);
}